// Round 1
// baseline (7385.116 us; speedup 1.0000x reference)
//
#include <hip/hip_runtime.h>
#include <cstdint>
#include <cstddef>

// ---------------------------------------------------------------------------
// GraphMathSolver: 4-layer MPNN on MI355X.
// Round 0: fp32 correctness baseline with fused tile-GEMM kernels.
// ws layout (floats): x[N*H] | agg[N*H] | ea[E*H] | pooled[B*H] | flag,ei32,batch32
// Roadmap: bf16 MFMA for msg/upd GEMMs, bf16 LDS staging, global_load_lds.
// ---------------------------------------------------------------------------

constexpr int kN  = 10000;
constexpr int kE  = 160000;
constexpr int kB  = 64;
constexpr int kH  = 256;
constexpr int kL  = 4;
constexpr int kC  = 10;
constexpr float kEps = 1e-5f;

struct __align__(16) F4 { float v[4]; };
__device__ __forceinline__ F4 ldF4(const float* p) { return *reinterpret_cast<const F4*>(p); }
__device__ __forceinline__ void stF4(float* p, const F4& x) { *reinterpret_cast<F4*>(p) = x; }

// ---------------- int64/int32 index handling (ref uses jnp.int64) ----------
__global__ void k_detect_i64(const unsigned* __restrict__ w, int* __restrict__ flag) {
    if (threadIdx.x == 0 && blockIdx.x == 0) {
        int is64 = 1;
        for (int i = 0; i < 64; ++i)
            if (w[2*i + 1] != 0u) { is64 = 0; break; }
        *flag = is64;
    }
}
__global__ void k_cvt_idx(const unsigned* __restrict__ w, const int* __restrict__ flag,
                          int* __restrict__ out, int n) {
    int i = blockIdx.x * 256 + threadIdx.x;
    if (i < n) out[i] = (*flag) ? (int)w[2*i] : (int)w[i];
}

// ---------------- encoders -------------------------------------------------
__global__ __launch_bounds__(256) void k_encode_nodes(
    const float* __restrict__ nf, const float* __restrict__ W,
    const float* __restrict__ b, float* __restrict__ x)
{
    __shared__ float s_nf[4 * 128];
    const int n0 = blockIdx.x * 4;
    const int tid = threadIdx.x;
    reinterpret_cast<float2*>(s_nf)[tid] =
        reinterpret_cast<const float2*>(nf + (size_t)n0 * 128)[tid];
    __syncthreads();
    float acc[4] = {0.f, 0.f, 0.f, 0.f};
    for (int k = 0; k < 128; ++k) {
        float w = W[k * kH + tid];
        #pragma unroll
        for (int r = 0; r < 4; ++r) acc[r] = fmaf(s_nf[r * 128 + k], w, acc[r]);
    }
    float bias = b[tid];
    #pragma unroll
    for (int r = 0; r < 4; ++r) x[(size_t)(n0 + r) * kH + tid] = acc[r] + bias;
}

__global__ __launch_bounds__(256) void k_encode_edges(
    const float* __restrict__ ef, const float* __restrict__ W,
    const float* __restrict__ b, float* __restrict__ ea)
{
    __shared__ float s_ef[8 * 64];
    const int e0 = blockIdx.x * 8;
    const int tid = threadIdx.x;
    reinterpret_cast<float2*>(s_ef)[tid] =
        reinterpret_cast<const float2*>(ef + (size_t)e0 * 64)[tid];
    __syncthreads();
    float acc[8] = {};
    for (int k = 0; k < 64; ++k) {
        float w = W[k * kH + tid];
        #pragma unroll
        for (int r = 0; r < 8; ++r) acc[r] = fmaf(s_ef[r * 64 + k], w, acc[r]);
    }
    float bias = b[tid];
    #pragma unroll
    for (int r = 0; r < 8; ++r) ea[(size_t)(e0 + r) * kH + tid] = acc[r] + bias;
}

// ---------------- shared tile-GEMM pieces ----------------------------------
// block = 256 threads = (ty 0..15) x (tx 0..15); tile 64 rows x 256 cols.
// thread micro-tile: rows ty*4..+3, cols tx*4 + g*64 (g=0..3) -> acc[4][16].
__device__ __forceinline__ void stage_B(const float* __restrict__ W, float* Bs, int tid) {
    const F4* gp = reinterpret_cast<const F4*>(W);
    F4* sp = reinterpret_cast<F4*>(Bs);
    #pragma unroll
    for (int i = 0; i < 8; ++i) sp[tid + i * 256] = gp[tid + i * 256];
}

template <int LDA>
__device__ __forceinline__ void mm_chunk(const float* __restrict__ A,
                                         const float* __restrict__ Bs,
                                         int ty4, int tx4, float acc[4][16])
{
    #pragma unroll 4
    for (int kk = 0; kk < 32; ++kk) {
        F4 a = ldF4(A + kk * LDA + ty4);
        #pragma unroll
        for (int g = 0; g < 4; ++g) {
            F4 b = ldF4(Bs + kk * kH + tx4 + g * 64);
            #pragma unroll
            for (int i = 0; i < 4; ++i)
                #pragma unroll
                for (int c = 0; c < 4; ++c)
                    acc[i][g * 4 + c] = fmaf(a.v[i], b.v[c], acc[i][g * 4 + c]);
        }
    }
}

// ---------------- edge message MLP + scatter-add ----------------------------
__global__ __launch_bounds__(256) void k_msg(
    const float* __restrict__ x, const float* __restrict__ ea,
    const int* __restrict__ src, const int* __restrict__ dst,
    const float* __restrict__ W1, const float* __restrict__ b1,
    const float* __restrict__ W2, const float* __restrict__ b2,
    float* __restrict__ agg)
{
    __shared__ float At[32 * 64];      // A^T chunk [kk][row]  8KB
    __shared__ float Bs[32 * kH];      // W chunk              32KB
    __shared__ float Ht[kH * 68];      // h1^T [col][row+pad]  69.6KB
    __shared__ int s_src[64], s_dst[64];

    const int tid = threadIdx.x;
    const int tx4 = (tid & 15) * 4, ty4 = (tid >> 4) * 4;
    const int e0 = blockIdx.x * 64;
    const int le = tid & 63, lq = tid >> 6;

    if (tid < 64) { s_src[tid] = src[e0 + tid]; s_dst[tid] = dst[e0 + tid]; }
    __syncthreads();

    float acc[4][16];
    #pragma unroll
    for (int i = 0; i < 4; ++i)
        #pragma unroll
        for (int j = 0; j < 16; ++j) acc[i][j] = 0.f;

    // GEMM1: h1 = relu([x[src] | x[dst] | ea] @ W1 + b1), K = 768
    for (int kb = 0; kb < 768; kb += 32) {
        __syncthreads();
        const float* rp;
        if (kb < 256)      rp = x  + (size_t)s_src[le] * kH + kb;
        else if (kb < 512) rp = x  + (size_t)s_dst[le] * kH + (kb - 256);
        else               rp = ea + (size_t)(e0 + le) * kH + (kb - 512);
        #pragma unroll
        for (int h = 0; h < 2; ++h) {
            int kk0 = (lq + h * 4) * 4;
            F4 v = ldF4(rp + kk0);
            #pragma unroll
            for (int i = 0; i < 4; ++i) At[(kk0 + i) * 64 + le] = v.v[i];
        }
        stage_B(W1 + (size_t)kb * kH, Bs, tid);
        __syncthreads();
        mm_chunk<64>(At, Bs, ty4, tx4, acc);
    }
    // bias + relu -> Ht (transposed), reset acc
    #pragma unroll
    for (int g = 0; g < 4; ++g) {
        F4 bb = ldF4(b1 + tx4 + g * 64);
        #pragma unroll
        for (int c = 0; c < 4; ++c)
            #pragma unroll
            for (int i = 0; i < 4; ++i) {
                float h = acc[i][g * 4 + c] + bb.v[c];
                Ht[(tx4 + g * 64 + c) * 68 + ty4 + i] = h > 0.f ? h : 0.f;
                acc[i][g * 4 + c] = 0.f;
            }
    }
    // GEMM2: msg = h1 @ W2 + b2, K = 256
    for (int kb = 0; kb < 256; kb += 32) {
        __syncthreads();
        stage_B(W2 + (size_t)kb * kH, Bs, tid);
        __syncthreads();
        mm_chunk<68>(Ht + kb * 68, Bs, ty4, tx4, acc);
    }
    // scatter-add into agg[dst]
    #pragma unroll
    for (int g = 0; g < 4; ++g) {
        F4 bb = ldF4(b2 + tx4 + g * 64);
        #pragma unroll
        for (int i = 0; i < 4; ++i) {
            float* ap = agg + (size_t)s_dst[ty4 + i] * kH + tx4 + g * 64;
            #pragma unroll
            for (int c = 0; c < 4; ++c)
                unsafeAtomicAdd(ap + c, acc[i][g * 4 + c] + bb.v[c]);
        }
    }
}

// ---------------- node update MLP + residual + LayerNorm --------------------
__global__ __launch_bounds__(256) void k_upd(
    float* __restrict__ x, const float* __restrict__ agg,
    const float* __restrict__ W1, const float* __restrict__ b1,
    const float* __restrict__ W2, const float* __restrict__ b2,
    const float* __restrict__ lng, const float* __restrict__ lnb)
{
    __shared__ float At[32 * 64];
    __shared__ float Bs[32 * kH];
    __shared__ float Ht[kH * 68];

    const int tid = threadIdx.x;
    const int tx4 = (tid & 15) * 4, ty4 = (tid >> 4) * 4;
    const int n0 = blockIdx.x * 64;
    const int le = tid & 63, lq = tid >> 6;
    int node_le = n0 + le; if (node_le >= kN) node_le = kN - 1;

    float acc[4][16];
    #pragma unroll
    for (int i = 0; i < 4; ++i)
        #pragma unroll
        for (int j = 0; j < 16; ++j) acc[i][j] = 0.f;

    // GEMM1: h = relu([x | agg] @ W1 + b1), K = 512
    for (int kb = 0; kb < 512; kb += 32) {
        __syncthreads();
        const float* rp = (kb < 256)
            ? x   + (size_t)node_le * kH + kb
            : agg + (size_t)node_le * kH + (kb - 256);
        #pragma unroll
        for (int h = 0; h < 2; ++h) {
            int kk0 = (lq + h * 4) * 4;
            F4 v = ldF4(rp + kk0);
            #pragma unroll
            for (int i = 0; i < 4; ++i) At[(kk0 + i) * 64 + le] = v.v[i];
        }
        stage_B(W1 + (size_t)kb * kH, Bs, tid);
        __syncthreads();
        mm_chunk<64>(At, Bs, ty4, tx4, acc);
    }
    #pragma unroll
    for (int g = 0; g < 4; ++g) {
        F4 bb = ldF4(b1 + tx4 + g * 64);
        #pragma unroll
        for (int c = 0; c < 4; ++c)
            #pragma unroll
            for (int i = 0; i < 4; ++i) {
                float h = acc[i][g * 4 + c] + bb.v[c];
                Ht[(tx4 + g * 64 + c) * 68 + ty4 + i] = h > 0.f ? h : 0.f;
                acc[i][g * 4 + c] = 0.f;
            }
    }
    // GEMM2: upd = h @ W2 + b2, K = 256
    for (int kb = 0; kb < 256; kb += 32) {
        __syncthreads();
        stage_B(W2 + (size_t)kb * kH, Bs, tid);
        __syncthreads();
        mm_chunk<68>(Ht + kb * 68, Bs, ty4, tx4, acc);
    }
    // epilogue: residual + LayerNorm, write x in place (block owns its rows)
    float val[4][16];
    #pragma unroll
    for (int i = 0; i < 4; ++i) {
        int node = n0 + ty4 + i;
        int nc = node < kN ? node : kN - 1;
        #pragma unroll
        for (int g = 0; g < 4; ++g) {
            F4 xr = ldF4(x + (size_t)nc * kH + tx4 + g * 64);
            F4 bb = ldF4(b2 + tx4 + g * 64);
            #pragma unroll
            for (int c = 0; c < 4; ++c)
                val[i][g * 4 + c] = xr.v[c] + acc[i][g * 4 + c] + bb.v[c];
        }
    }
    float mean[4], rstd[4];
    #pragma unroll
    for (int i = 0; i < 4; ++i) {
        float s = 0.f, q = 0.f;
        #pragma unroll
        for (int j = 0; j < 16; ++j) { s += val[i][j]; q += val[i][j] * val[i][j]; }
        #pragma unroll
        for (int m = 1; m < 16; m <<= 1) { s += __shfl_xor(s, m); q += __shfl_xor(q, m); }
        mean[i] = s * (1.f / 256.f);
        float var = q * (1.f / 256.f) - mean[i] * mean[i];
        rstd[i] = rsqrtf(var + kEps);
    }
    #pragma unroll
    for (int i = 0; i < 4; ++i) {
        int node = n0 + ty4 + i;
        if (node >= kN) continue;
        #pragma unroll
        for (int g = 0; g < 4; ++g) {
            F4 gg = ldF4(lng + tx4 + g * 64);
            F4 bv = ldF4(lnb + tx4 + g * 64);
            F4 o;
            #pragma unroll
            for (int c = 0; c < 4; ++c)
                o.v[c] = (val[i][g * 4 + c] - mean[i]) * rstd[i] * gg.v[c] + bv.v[c];
            stF4(x + (size_t)node * kH + tx4 + g * 64, o);
        }
    }
}

// ---------------- pooling + readout -----------------------------------------
__device__ __forceinline__ int lower_bound_i(const int* a, int n, int v) {
    int lo = 0, hi = n;
    while (lo < hi) { int m = (lo + hi) >> 1; if (a[m] < v) lo = m + 1; else hi = m; }
    return lo;
}

__global__ __launch_bounds__(256) void k_pool(
    const float* __restrict__ x, const int* __restrict__ batch,
    float* __restrict__ pooled)
{
    const int b = blockIdx.x, t = threadIdx.x;
    const int s = lower_bound_i(batch, kN, b);
    const int e = lower_bound_i(batch, kN, b + 1);
    float acc = 0.f;
    for (int i = s; i < e; ++i) acc += x[(size_t)i * kH + t];
    pooled[b * kH + t] = acc / (float)(e - s);
}

__global__ __launch_bounds__(256) void k_readout(
    const float* __restrict__ pooled,
    const float* __restrict__ W1, const float* __restrict__ b1,
    const float* __restrict__ W2, const float* __restrict__ b2,
    float* __restrict__ out)
{
    __shared__ float ph[kH];
    __shared__ float h1[kH];
    const int b = blockIdx.x, t = threadIdx.x;
    ph[t] = pooled[b * kH + t];
    __syncthreads();
    float a = b1[t];
    for (int k = 0; k < kH; ++k) a = fmaf(ph[k], W1[k * kH + t], a);
    h1[t] = a > 0.f ? a : 0.f;
    __syncthreads();
    if (t < kC) {
        float o = b2[t];
        for (int k = 0; k < kH; ++k) o = fmaf(h1[k], W2[k * kC + t], o);
        out[b * kC + t] = o;
    }
}

// ---------------- launch ----------------------------------------------------
extern "C" void kernel_launch(void* const* d_in, const int* in_sizes, int n_in,
                              void* d_out, int out_size, void* d_ws, size_t ws_size,
                              hipStream_t stream)
{
    const float* nf     = (const float*)d_in[0];
    const void*  ei_raw = d_in[1];
    const float* ef     = (const float*)d_in[2];
    const void*  ba_raw = d_in[3];
    const float* node_W = (const float*)d_in[4];
    const float* node_b = (const float*)d_in[5];
    const float* edge_W = (const float*)d_in[6];
    const float* edge_b = (const float*)d_in[7];
    const float* msg_W1 = (const float*)d_in[8];
    const float* msg_b1 = (const float*)d_in[9];
    const float* msg_W2 = (const float*)d_in[10];
    const float* msg_b2 = (const float*)d_in[11];
    const float* upd_W1 = (const float*)d_in[12];
    const float* upd_b1 = (const float*)d_in[13];
    const float* upd_W2 = (const float*)d_in[14];
    const float* upd_b2 = (const float*)d_in[15];
    const float* ln_g   = (const float*)d_in[16];
    const float* ln_b   = (const float*)d_in[17];
    const float* ro_W1  = (const float*)d_in[18];
    const float* ro_b1  = (const float*)d_in[19];
    const float* ro_W2  = (const float*)d_in[20];
    const float* ro_b2  = (const float*)d_in[21];

    float* ws     = (float*)d_ws;
    float* x      = ws;                               // N*H
    float* agg    = x + (size_t)kN * kH;              // N*H
    float* ea     = agg + (size_t)kN * kH;            // E*H
    float* pooled = ea + (size_t)kE * kH;             // B*H
    int*   flag   = (int*)(pooled + (size_t)kB * kH); // 1
    int*   ei32   = flag + 1;                         // 2*E
    int*   ba32   = ei32 + 2 * kE;                    // N

    // normalize index dtype (int64 from jax, or int32 if harness converts)
    k_detect_i64<<<1, 64, 0, stream>>>((const unsigned*)ei_raw, flag);
    k_cvt_idx<<<(2 * kE + 255) / 256, 256, 0, stream>>>((const unsigned*)ei_raw, flag, ei32, 2 * kE);
    k_cvt_idx<<<(kN + 255) / 256, 256, 0, stream>>>((const unsigned*)ba_raw, flag, ba32, kN);
    const int* src = ei32;
    const int* dst = ei32 + kE;

    k_encode_nodes<<<kN / 4, 256, 0, stream>>>(nf, node_W, node_b, x);
    k_encode_edges<<<kE / 8, 256, 0, stream>>>(ef, edge_W, edge_b, ea);

    for (int l = 0; l < kL; ++l) {
        hipMemsetAsync(agg, 0, (size_t)kN * kH * sizeof(float), stream);
        k_msg<<<kE / 64, 256, 0, stream>>>(x, ea, src, dst,
            msg_W1 + (size_t)l * 3 * kH * kH, msg_b1 + l * kH,
            msg_W2 + (size_t)l * kH * kH,     msg_b2 + l * kH, agg);
        k_upd<<<(kN + 63) / 64, 256, 0, stream>>>(x, agg,
            upd_W1 + (size_t)l * 2 * kH * kH, upd_b1 + l * kH,
            upd_W2 + (size_t)l * kH * kH,     upd_b2 + l * kH,
            ln_g + l * kH, ln_b + l * kH);
    }

    k_pool<<<kB, 256, 0, stream>>>(x, ba32, pooled);
    k_readout<<<kB, 256, 0, stream>>>(pooled, ro_W1, ro_b1, ro_W2, ro_b2, (float*)d_out);
}

// Round 2
// 1049.788 us; speedup vs baseline: 7.0349x; 7.0349x over previous
//
#include <hip/hip_runtime.h>
#include <cstdint>
#include <cstddef>

// ---------------------------------------------------------------------------
// GraphMathSolver: 4-layer MPNN on MI355X.
// Round 2: bf16 MFMA (16x16x32) for all MLP GEMMs, fp32 accumulate.
//   - weights pre-transposed to bf16 k-chunk-major [kc][n][32] once per call
//   - GEMM1 swapped (h1^T = W1^T @ in^T) so gather-staging [row][k] feeds B
//   - XOR-swizzled LDS tiles, 2-barrier loop, 3 blocks/CU
//   - k-order-invariant fragment loading (robust to HW k-layout ambiguity)
// ---------------------------------------------------------------------------

typedef unsigned short u16;
typedef __attribute__((ext_vector_type(4))) float f32x4;
typedef __attribute__((ext_vector_type(8))) short bf16x8;
typedef __attribute__((ext_vector_type(4))) short s16x4;

constexpr int kN  = 10000;
constexpr int kE  = 160000;
constexpr int kB  = 64;
constexpr int kH  = 256;
constexpr int kL  = 4;
constexpr int kC  = 10;
constexpr float kEps = 1e-5f;

struct __align__(16) F4 { float v[4]; };
__device__ __forceinline__ F4 ldF4(const float* p) { return *reinterpret_cast<const F4*>(p); }

__device__ __forceinline__ u16 f2bf(float f) {
    unsigned u = __builtin_bit_cast(unsigned, f);
    return (u16)((u + 0x7fffu + ((u >> 16) & 1u)) >> 16);
}

// ---------------- int64/int32 index handling (ref uses jnp.int64) ----------
__global__ void k_detect_i64(const unsigned* __restrict__ w, int* __restrict__ flag) {
    if (threadIdx.x == 0 && blockIdx.x == 0) {
        int is64 = 1;
        for (int i = 0; i < 64; ++i)
            if (w[2*i + 1] != 0u) { is64 = 0; break; }
        *flag = is64;
    }
}
__global__ void k_cvt_idx(const unsigned* __restrict__ w, const int* __restrict__ flag,
                          int* __restrict__ out, int n) {
    int i = blockIdx.x * 256 + threadIdx.x;
    if (i < n) out[i] = (*flag) ? (int)w[2*i] : (int)w[i];
}

// ---------------- weight prep: fp32 [L][K][256] -> bf16 [L][kc][n][32] -----
__global__ __launch_bounds__(256) void k_prep_w(
    const float* __restrict__ mW1, const float* __restrict__ mW2,
    const float* __restrict__ uW1, const float* __restrict__ uW2,
    u16* __restrict__ tm1, u16* __restrict__ tm2,
    u16* __restrict__ tu1, u16* __restrict__ tu2)
{
    int idx = blockIdx.x * 256 + threadIdx.x;
    const int S1 = kL * 768 * 256;
    const int S2 = S1 + kL * 256 * 256;
    const int S3 = S2 + kL * 512 * 256;
    const int S4 = S3 + kL * 256 * 256;
    const float* src; u16* dst; int K, r;
    if (idx < S1)      { src = mW1; dst = tm1; K = 768; r = idx; }
    else if (idx < S2) { src = mW2; dst = tm2; K = 256; r = idx - S1; }
    else if (idx < S3) { src = uW1; dst = tu1; K = 512; r = idx - S2; }
    else if (idx < S4) { src = uW2; dst = tu2; K = 256; r = idx - S3; }
    else return;
    int per = K * 256;
    int layer = r / per, rr = r - layer * per;
    int k = rr >> 8, n = rr & 255;
    float v = src[(size_t)layer * per + rr];
    dst[(size_t)layer * per + (size_t)(k >> 5) * 8192 + n * 32 + (k & 31)] = f2bf(v);
}

// ---------------- encoders -------------------------------------------------
__global__ __launch_bounds__(256) void k_encode_nodes(
    const float* __restrict__ nf, const float* __restrict__ W,
    const float* __restrict__ b, float* __restrict__ x, u16* __restrict__ x_bf)
{
    __shared__ float s_nf[4 * 128];
    const int n0 = blockIdx.x * 4;
    const int tid = threadIdx.x;
    reinterpret_cast<float2*>(s_nf)[tid] =
        reinterpret_cast<const float2*>(nf + (size_t)n0 * 128)[tid];
    __syncthreads();
    float acc[4] = {0.f, 0.f, 0.f, 0.f};
    for (int k = 0; k < 128; ++k) {
        float w = W[k * kH + tid];
        #pragma unroll
        for (int r = 0; r < 4; ++r) acc[r] = fmaf(s_nf[r * 128 + k], w, acc[r]);
    }
    float bias = b[tid];
    #pragma unroll
    for (int r = 0; r < 4; ++r) {
        float o = acc[r] + bias;
        x[(size_t)(n0 + r) * kH + tid] = o;
        x_bf[(size_t)(n0 + r) * kH + tid] = f2bf(o);
    }
}

__global__ __launch_bounds__(256) void k_encode_edges(
    const float* __restrict__ ef, const float* __restrict__ W,
    const float* __restrict__ b, u16* __restrict__ ea_bf)
{
    __shared__ float s_ef[8 * 64];
    const int e0 = blockIdx.x * 8;
    const int tid = threadIdx.x;
    reinterpret_cast<float2*>(s_ef)[tid] =
        reinterpret_cast<const float2*>(ef + (size_t)e0 * 64)[tid];
    __syncthreads();
    float acc[8] = {};
    for (int k = 0; k < 64; ++k) {
        float w = W[k * kH + tid];
        #pragma unroll
        for (int r = 0; r < 8; ++r) acc[r] = fmaf(s_ef[r * 64 + k], w, acc[r]);
    }
    float bias = b[tid];
    #pragma unroll
    for (int r = 0; r < 8; ++r)
        ea_bf[(size_t)(e0 + r) * kH + tid] = f2bf(acc[r] + bias);
}

// ---------------- shared MFMA-GEMM helpers ---------------------------------
// Wt chunk LDS tile: [n=256][kk=32] bf16, 16B slot (n,kg) at n*64 + (kg^((n>>1)&3))*16
__device__ __forceinline__ void stage_wt(const u16* __restrict__ gW, char* lds, int tid) {
    const int4* g = reinterpret_cast<const int4*>(gW);
    #pragma unroll
    for (int i = 0; i < 4; ++i) {
        int s = tid + i * 256;
        int n = s >> 2, kg = s & 3;
        int4 v = g[s];
        *reinterpret_cast<int4*>(lds + n * 64 + ((kg ^ ((n >> 1) & 3)) << 4)) = v;
    }
}
__device__ __forceinline__ bf16x8 rdfrag(const char* lds, int n, int kg) {
    return *reinterpret_cast<const bf16x8*>(lds + n * 64 + ((kg ^ ((n >> 1) & 3)) << 4));
}
// H tile: [edge=64][hcol=256] bf16, byte addr XOR ((edge&7)<<4)
__device__ __forceinline__ bf16x8 rdH(const char* H, int edge, int kbyte) {
    return *reinterpret_cast<const bf16x8*>(H + edge * 512 + (kbyte ^ ((edge & 7) << 4)));
}

// ---------------- edge message MLP + scatter-add ---------------------------
__global__ __launch_bounds__(256, 3) void k_msg(
    const u16* __restrict__ x_bf, const u16* __restrict__ ea_bf,
    const int* __restrict__ src, const int* __restrict__ dst,
    const u16* __restrict__ Wt1, const float* __restrict__ b1,
    const u16* __restrict__ Wt2, const float* __restrict__ b2,
    float* __restrict__ agg)
{
    __shared__ char sWt[16384];   // weight chunk [256][32] bf16
    __shared__ char sA[4096];     // gathered chunk [64][32] bf16 (reused for dst idx)
    __shared__ char sH[32768];    // h1 [64 edges][256] bf16

    const int tid = threadIdx.x;
    const int e0 = blockIdx.x * 64;
    const int w = tid >> 6;
    const int l = tid & 63;
    const int lr = l & 15, lg = l >> 4;
    const int srow = tid >> 2, skg = tid & 3;

    const int my_src = src[e0 + srow];
    const int my_dst = dst[e0 + srow];

    f32x4 acc[4][4];
    #pragma unroll
    for (int i = 0; i < 4; ++i)
        #pragma unroll
        for (int j = 0; j < 4; ++j) acc[i][j] = (f32x4){0.f, 0.f, 0.f, 0.f};

    // ---- GEMM1 (swapped): h1^T[hcol][edge], K = 768 = 24 chunks ----
    for (int kc = 0; kc < 24; ++kc) {
        __syncthreads();
        const u16* rp;
        if (kc < 8)       rp = x_bf + (size_t)my_src * kH + kc * 32;
        else if (kc < 16) rp = x_bf + (size_t)my_dst * kH + (kc - 8) * 32;
        else              rp = ea_bf + (size_t)(e0 + srow) * kH + (kc - 16) * 32;
        int4 bv = *reinterpret_cast<const int4*>(rp + skg * 8);
        *reinterpret_cast<int4*>(sA + srow * 64 + ((skg ^ ((srow >> 1) & 3)) << 4)) = bv;
        stage_wt(Wt1 + (size_t)kc * 8192, sWt, tid);
        __syncthreads();
        bf16x8 af[4], bfm[4];
        #pragma unroll
        for (int i = 0; i < 4; ++i) af[i] = rdfrag(sWt, w * 64 + i * 16 + lr, lg);
        #pragma unroll
        for (int j = 0; j < 4; ++j) bfm[j] = rdfrag(sA, j * 16 + lr, lg);
        #pragma unroll
        for (int i = 0; i < 4; ++i)
            #pragma unroll
            for (int j = 0; j < 4; ++j)
                acc[i][j] = __builtin_amdgcn_mfma_f32_16x16x32_bf16(af[i], bfm[j], acc[i][j], 0, 0, 0);
    }

    // ---- epilogue 1: bias + relu -> sH[edge][hcol] ----
    #pragma unroll
    for (int i = 0; i < 4; ++i) {
        const int hc0 = w * 64 + i * 16 + lg * 4;
        const F4 bb = ldF4(b1 + hc0);
        #pragma unroll
        for (int j = 0; j < 4; ++j) {
            const int edge = j * 16 + lr;
            s16x4 o;
            #pragma unroll
            for (int q = 0; q < 4; ++q) {
                float h = acc[i][j][q] + bb.v[q];
                h = h > 0.f ? h : 0.f;
                o[q] = (short)f2bf(h);
            }
            int byte = edge * 512 + hc0 * 2;
            *reinterpret_cast<s16x4*>(sH + (byte ^ ((edge & 7) << 4))) = o;
            acc[i][j] = (f32x4){0.f, 0.f, 0.f, 0.f};
        }
    }

    // ---- GEMM2 (normal): msg[edge][oc] = h1 @ W2, K = 256 = 8 chunks ----
    for (int kc = 0; kc < 8; ++kc) {
        __syncthreads();
        stage_wt(Wt2 + (size_t)kc * 8192, sWt, tid);
        __syncthreads();
        bf16x8 af2[4], bf2[4];
        #pragma unroll
        for (int i = 0; i < 4; ++i) af2[i] = rdH(sH, i * 16 + lr, kc * 64 + lg * 16);
        #pragma unroll
        for (int j = 0; j < 4; ++j) bf2[j] = rdfrag(sWt, w * 64 + j * 16 + lr, lg);
        #pragma unroll
        for (int i = 0; i < 4; ++i)
            #pragma unroll
            for (int j = 0; j < 4; ++j)
                acc[i][j] = __builtin_amdgcn_mfma_f32_16x16x32_bf16(af2[i], bf2[j], acc[i][j], 0, 0, 0);
    }

    // ---- scatter-add into agg[dst] ----
    __syncthreads();
    if (tid < 64) reinterpret_cast<int*>(sA)[tid] = dst[e0 + tid];
    __syncthreads();
    const int* sd = reinterpret_cast<const int*>(sA);
    #pragma unroll
    for (int j = 0; j < 4; ++j) {
        const int oc = w * 64 + j * 16 + lr;
        const float b2v = b2[oc];
        #pragma unroll
        for (int i = 0; i < 4; ++i)
            #pragma unroll
            for (int q = 0; q < 4; ++q) {
                int e = i * 16 + lg * 4 + q;
                unsafeAtomicAdd(agg + (size_t)sd[e] * kH + oc, acc[i][j][q] + b2v);
            }
    }
}

// ---------------- node update MLP + residual + LayerNorm --------------------
__global__ __launch_bounds__(256, 3) void k_upd(
    float* __restrict__ x, u16* __restrict__ x_bf,
    const float* __restrict__ agg,
    const u16* __restrict__ Wt1, const float* __restrict__ b1,
    const u16* __restrict__ Wt2, const float* __restrict__ b2,
    const float* __restrict__ lng, const float* __restrict__ lnb)
{
    __shared__ char sWt[16384];
    __shared__ char sA[4096];     // staged chunk; later reused for LN reduction
    __shared__ char sH[32768];

    const int tid = threadIdx.x;
    const int n0 = blockIdx.x * 64;
    const int w = tid >> 6;
    const int l = tid & 63;
    const int lr = l & 15, lg = l >> 4;
    const int srow = tid >> 2, skg = tid & 3;
    int gnode = n0 + srow; if (gnode >= kN) gnode = kN - 1;

    f32x4 acc[4][4];
    #pragma unroll
    for (int i = 0; i < 4; ++i)
        #pragma unroll
        for (int j = 0; j < 4; ++j) acc[i][j] = (f32x4){0.f, 0.f, 0.f, 0.f};

    // ---- GEMM1 (swapped): K = 512 = 16 chunks ([x | agg]) ----
    for (int kc = 0; kc < 16; ++kc) {
        __syncthreads();
        int4 bv;
        if (kc < 8) {
            bv = *reinterpret_cast<const int4*>(x_bf + (size_t)gnode * kH + kc * 32 + skg * 8);
        } else {
            const float* ap = agg + (size_t)gnode * kH + (kc - 8) * 32 + skg * 8;
            F4 a0 = ldF4(ap); F4 a1 = ldF4(ap + 4);
            bv.x = (int)f2bf(a0.v[0]) | ((int)f2bf(a0.v[1]) << 16);
            bv.y = (int)f2bf(a0.v[2]) | ((int)f2bf(a0.v[3]) << 16);
            bv.z = (int)f2bf(a1.v[0]) | ((int)f2bf(a1.v[1]) << 16);
            bv.w = (int)f2bf(a1.v[2]) | ((int)f2bf(a1.v[3]) << 16);
        }
        *reinterpret_cast<int4*>(sA + srow * 64 + ((skg ^ ((srow >> 1) & 3)) << 4)) = bv;
        stage_wt(Wt1 + (size_t)kc * 8192, sWt, tid);
        __syncthreads();
        bf16x8 af[4], bfm[4];
        #pragma unroll
        for (int i = 0; i < 4; ++i) af[i] = rdfrag(sWt, w * 64 + i * 16 + lr, lg);
        #pragma unroll
        for (int j = 0; j < 4; ++j) bfm[j] = rdfrag(sA, j * 16 + lr, lg);
        #pragma unroll
        for (int i = 0; i < 4; ++i)
            #pragma unroll
            for (int j = 0; j < 4; ++j)
                acc[i][j] = __builtin_amdgcn_mfma_f32_16x16x32_bf16(af[i], bfm[j], acc[i][j], 0, 0, 0);
    }

    // ---- epilogue 1: bias + relu -> sH ----
    #pragma unroll
    for (int i = 0; i < 4; ++i) {
        const int hc0 = w * 64 + i * 16 + lg * 4;
        const F4 bb = ldF4(b1 + hc0);
        #pragma unroll
        for (int j = 0; j < 4; ++j) {
            const int row = j * 16 + lr;
            s16x4 o;
            #pragma unroll
            for (int q = 0; q < 4; ++q) {
                float h = acc[i][j][q] + bb.v[q];
                h = h > 0.f ? h : 0.f;
                o[q] = (short)f2bf(h);
            }
            int byte = row * 512 + hc0 * 2;
            *reinterpret_cast<s16x4*>(sH + (byte ^ ((row & 7) << 4))) = o;
            acc[i][j] = (f32x4){0.f, 0.f, 0.f, 0.f};
        }
    }

    // ---- GEMM2 (normal): upd[node][oc], K = 256 = 8 chunks ----
    for (int kc = 0; kc < 8; ++kc) {
        __syncthreads();
        stage_wt(Wt2 + (size_t)kc * 8192, sWt, tid);
        __syncthreads();
        bf16x8 af2[4], bf2[4];
        #pragma unroll
        for (int i = 0; i < 4; ++i) af2[i] = rdH(sH, i * 16 + lr, kc * 64 + lg * 16);
        #pragma unroll
        for (int j = 0; j < 4; ++j) bf2[j] = rdfrag(sWt, w * 64 + j * 16 + lr, lg);
        #pragma unroll
        for (int i = 0; i < 4; ++i)
            #pragma unroll
            for (int j = 0; j < 4; ++j)
                acc[i][j] = __builtin_amdgcn_mfma_f32_16x16x32_bf16(af2[i], bf2[j], acc[i][j], 0, 0, 0);
    }

    // ---- epilogue 2: + b2 + x (residual), LayerNorm, store x / x_bf ----
    float b2v[4], gv[4], bvn[4];
    #pragma unroll
    for (int j = 0; j < 4; ++j) {
        int oc = w * 64 + j * 16 + lr;
        b2v[j] = b2[oc]; gv[j] = lng[oc]; bvn[j] = lnb[oc];
    }
    #pragma unroll
    for (int i = 0; i < 4; ++i)
        #pragma unroll
        for (int j = 0; j < 4; ++j) {
            int oc = w * 64 + j * 16 + lr;
            #pragma unroll
            for (int q = 0; q < 4; ++q) {
                int node = n0 + i * 16 + lg * 4 + q;
                int ncl = node < kN ? node : kN - 1;
                acc[i][j][q] += b2v[j] + x[(size_t)ncl * kH + oc];
            }
        }

    float (*red)[64][2] = reinterpret_cast<float(*)[64][2]>(sA);
    float2* mstd = reinterpret_cast<float2*>(sA + 2048);
    __syncthreads();
    #pragma unroll
    for (int i = 0; i < 4; ++i)
        #pragma unroll
        for (int q = 0; q < 4; ++q) {
            float s = acc[i][0][q] + acc[i][1][q] + acc[i][2][q] + acc[i][3][q];
            float ss = acc[i][0][q] * acc[i][0][q] + acc[i][1][q] * acc[i][1][q]
                     + acc[i][2][q] * acc[i][2][q] + acc[i][3][q] * acc[i][3][q];
            #pragma unroll
            for (int m = 1; m < 16; m <<= 1) { s += __shfl_xor(s, m); ss += __shfl_xor(ss, m); }
            if (lr == 0) { red[w][i * 16 + lg * 4 + q][0] = s; red[w][i * 16 + lg * 4 + q][1] = ss; }
        }
    __syncthreads();
    if (tid < 64) {
        float s = red[0][tid][0] + red[1][tid][0] + red[2][tid][0] + red[3][tid][0];
        float ss = red[0][tid][1] + red[1][tid][1] + red[2][tid][1] + red[3][tid][1];
        float mean = s * (1.f / 256.f);
        float var = ss * (1.f / 256.f) - mean * mean;
        mstd[tid] = make_float2(mean, rsqrtf(var + kEps));
    }
    __syncthreads();
    #pragma unroll
    for (int i = 0; i < 4; ++i)
        #pragma unroll
        for (int j = 0; j < 4; ++j) {
            int oc = w * 64 + j * 16 + lr;
            #pragma unroll
            for (int q = 0; q < 4; ++q) {
                int nn = i * 16 + lg * 4 + q;
                int node = n0 + nn;
                if (node < kN) {
                    float2 ms = mstd[nn];
                    float o = (acc[i][j][q] - ms.x) * ms.y * gv[j] + bvn[j];
                    x[(size_t)node * kH + oc] = o;
                    x_bf[(size_t)node * kH + oc] = f2bf(o);
                }
            }
        }
}

// ---------------- pooling + readout -----------------------------------------
__device__ __forceinline__ int lower_bound_i(const int* a, int n, int v) {
    int lo = 0, hi = n;
    while (lo < hi) { int m = (lo + hi) >> 1; if (a[m] < v) lo = m + 1; else hi = m; }
    return lo;
}

__global__ __launch_bounds__(256) void k_pool(
    const float* __restrict__ x, const int* __restrict__ batch,
    float* __restrict__ pooled)
{
    const int b = blockIdx.x, t = threadIdx.x;
    const int s = lower_bound_i(batch, kN, b);
    const int e = lower_bound_i(batch, kN, b + 1);
    float acc = 0.f;
    for (int i = s; i < e; ++i) acc += x[(size_t)i * kH + t];
    pooled[b * kH + t] = acc / (float)(e - s);
}

__global__ __launch_bounds__(256) void k_readout(
    const float* __restrict__ pooled,
    const float* __restrict__ W1, const float* __restrict__ b1,
    const float* __restrict__ W2, const float* __restrict__ b2,
    float* __restrict__ out)
{
    __shared__ float ph[kH];
    __shared__ float h1[kH];
    const int b = blockIdx.x, t = threadIdx.x;
    ph[t] = pooled[b * kH + t];
    __syncthreads();
    float a = b1[t];
    for (int k = 0; k < kH; ++k) a = fmaf(ph[k], W1[k * kH + t], a);
    h1[t] = a > 0.f ? a : 0.f;
    __syncthreads();
    if (t < kC) {
        float o = b2[t];
        for (int k = 0; k < kH; ++k) o = fmaf(h1[k], W2[k * kC + t], o);
        out[b * kC + t] = o;
    }
}

// ---------------- launch ----------------------------------------------------
extern "C" void kernel_launch(void* const* d_in, const int* in_sizes, int n_in,
                              void* d_out, int out_size, void* d_ws, size_t ws_size,
                              hipStream_t stream)
{
    const float* nf     = (const float*)d_in[0];
    const void*  ei_raw = d_in[1];
    const float* ef     = (const float*)d_in[2];
    const void*  ba_raw = d_in[3];
    const float* node_W = (const float*)d_in[4];
    const float* node_b = (const float*)d_in[5];
    const float* edge_W = (const float*)d_in[6];
    const float* edge_b = (const float*)d_in[7];
    const float* msg_W1 = (const float*)d_in[8];
    const float* msg_b1 = (const float*)d_in[9];
    const float* msg_W2 = (const float*)d_in[10];
    const float* msg_b2 = (const float*)d_in[11];
    const float* upd_W1 = (const float*)d_in[12];
    const float* upd_b1 = (const float*)d_in[13];
    const float* upd_W2 = (const float*)d_in[14];
    const float* upd_b2 = (const float*)d_in[15];
    const float* ln_g   = (const float*)d_in[16];
    const float* ln_b   = (const float*)d_in[17];
    const float* ro_W1  = (const float*)d_in[18];
    const float* ro_b1  = (const float*)d_in[19];
    const float* ro_W2  = (const float*)d_in[20];
    const float* ro_b2  = (const float*)d_in[21];

    char* p = (char*)d_ws;
    auto alloc = [&](size_t bytes) { char* r = p; p += (bytes + 255) & ~(size_t)255; return r; };
    float* x      = (float*)alloc((size_t)kN * kH * 4);
    float* agg    = (float*)alloc((size_t)kN * kH * 4);
    float* pooled = (float*)alloc((size_t)kB * kH * 4);
    u16* x_bf  = (u16*)alloc((size_t)kN * kH * 2);
    u16* ea_bf = (u16*)alloc((size_t)kE * kH * 2);
    u16* tm1 = (u16*)alloc((size_t)kL * 768 * 256 * 2);
    u16* tm2 = (u16*)alloc((size_t)kL * 256 * 256 * 2);
    u16* tu1 = (u16*)alloc((size_t)kL * 512 * 256 * 2);
    u16* tu2 = (u16*)alloc((size_t)kL * 256 * 256 * 2);
    int* ei32 = (int*)alloc((size_t)2 * kE * 4);
    int* ba32 = (int*)alloc((size_t)kN * 4);
    int* flag = (int*)alloc(4);

    k_detect_i64<<<1, 64, 0, stream>>>((const unsigned*)ei_raw, flag);
    k_cvt_idx<<<(2 * kE + 255) / 256, 256, 0, stream>>>((const unsigned*)ei_raw, flag, ei32, 2 * kE);
    k_cvt_idx<<<(kN + 255) / 256, 256, 0, stream>>>((const unsigned*)ba_raw, flag, ba32, kN);
    const int* src = ei32;
    const int* dst = ei32 + kE;

    k_prep_w<<<(kL * (768 + 256 + 512 + 256) * 256 + 255) / 256, 256, 0, stream>>>(
        msg_W1, msg_W2, upd_W1, upd_W2, tm1, tm2, tu1, tu2);

    k_encode_nodes<<<kN / 4, 256, 0, stream>>>(nf, node_W, node_b, x, x_bf);
    k_encode_edges<<<kE / 8, 256, 0, stream>>>(ef, edge_W, edge_b, ea_bf);

    for (int l = 0; l < kL; ++l) {
        hipMemsetAsync(agg, 0, (size_t)kN * kH * sizeof(float), stream);
        k_msg<<<kE / 64, 256, 0, stream>>>(x_bf, ea_bf, src, dst,
            tm1 + (size_t)l * 768 * 256, msg_b1 + l * kH,
            tm2 + (size_t)l * 256 * 256, msg_b2 + l * kH, agg);
        k_upd<<<(kN + 63) / 64, 256, 0, stream>>>(x, x_bf, agg,
            tu1 + (size_t)l * 512 * 256, upd_b1 + l * kH,
            tu2 + (size_t)l * 256 * 256, upd_b2 + l * kH,
            ln_g + l * kH, ln_b + l * kH);
    }

    k_pool<<<kB, 256, 0, stream>>>(x, ba32, pooled);
    k_readout<<<kB, 256, 0, stream>>>(pooled, ro_W1, ro_b1, ro_W2, ro_b2, (float*)d_out);
}